// Round 1
// 1570.364 us; speedup vs baseline: 1.4921x; 1.4921x over previous
//
#include <hip/hip_runtime.h>
#include <cmath>
#include <cstddef>
#include <cstdint>

// ---------------------------------------------------------------------------
// Round 3: move the VAE transcendental epilogues OUT of the GEMMs.
// rocprof showed gemm16<5> at ~940us with WRITE_SIZE = 4.1 GB (256x the 16 MB
// logical output), MfmaUtil 2.9%, VALUBusy 4.4% -> scratch/spill traffic from
// expf/log1pf + gathered loads executing with 128 live accumulators.
// Fix: gemm2 -> plain fp32-bias epilogue (EPI=7), gemm5b -> plain fp16-bias
// epilogue (EPI=3, written in-place into comb16 bottom half); two streaming
// elementwise kernels (ew_w, ew_reg) do the gather + exp/softplus math with
// coalesced f16x8/float4 accesses and trivial register pressure.
// ---------------------------------------------------------------------------

typedef _Float16 f16x8 __attribute__((ext_vector_type(8)));
typedef _Float16 f16x4 __attribute__((ext_vector_type(4)));
typedef float    f32x16 __attribute__((ext_vector_type(16)));

__device__ __forceinline__ void load_lds16(const _Float16* g, _Float16* l)
{
    __builtin_amdgcn_global_load_lds(
        (const __attribute__((address_space(1))) void*)g,
        (__attribute__((address_space(3))) void*)l, 16, 0, 0);
}

// Stable binary argsort of mask (mm%2): perm = [evens..., odds...].
__global__ __launch_bounds__(1024)
void perm_kernel(const int* __restrict__ mm, int* __restrict__ perm)
{
    __shared__ int sdata[1024];
    const int t = threadIdx.x;
    int m[4]; int cnt = 0;
#pragma unroll
    for (int j = 0; j < 4; ++j) { int i = t*4 + j; m[j] = mm[i] & 1; cnt += m[j]; }
    sdata[t] = cnt;
    __syncthreads();
    for (int off = 1; off < 1024; off <<= 1) {
        int v = (t >= off) ? sdata[t - off] : 0;
        __syncthreads();
        sdata[t] += v;
        __syncthreads();
    }
    const int n0 = 4096 - sdata[1023];
    int ones_before  = sdata[t] - cnt;
    int zeros_before = t*4 - ones_before;
#pragma unroll
    for (int j = 0; j < 4; ++j) {
        int i = t*4 + j;
        if (m[j]) perm[n0 + (ones_before++)] = i;
        else      perm[(zeros_before++)]     = i;
    }
}

// x fp32 -> comb16 top half (unmasked rows) and xm16 (masked rows), fp16.
__global__ __launch_bounds__(256)
void gather_kernel(const float* __restrict__ x, const int* __restrict__ perm,
                   _Float16* __restrict__ comb, _Float16* __restrict__ xm)
{
    const int p  = blockIdx.y;
    const int c4 = blockIdx.x * 256 + threadIdx.x;   // float4 col 0..1023
    const int src = perm[p];
    const float4 v = *(const float4*)(x + (size_t)src * 4096 + (size_t)c4 * 4);
    f16x4 h = { (_Float16)v.x, (_Float16)v.y, (_Float16)v.z, (_Float16)v.w };
    if (p < 2048) *(f16x4*)(comb + (size_t)p * 4096 + (size_t)c4 * 4) = h;
    else          *(f16x4*)(xm + (size_t)(p - 2048) * 4096 + (size_t)c4 * 4) = h;
}

// Flat fp32 -> fp16 convert, 4 elems/thread.
__global__ __launch_bounds__(256)
void cvt_kernel(const float* __restrict__ src, _Float16* __restrict__ dst, int n4)
{
    int i = blockIdx.x * 256 + threadIdx.x;
    if (i >= n4) return;
    float4 v = ((const float4*)src)[i];
    f16x4 h = { (_Float16)v.x, (_Float16)v.y, (_Float16)v.z, (_Float16)v.w };
    ((f16x4*)dst)[i] = h;
}

// W2 [1000,4096] fp32 -> [1024,4096] fp16, rows 1000..1023 zeroed.
__global__ __launch_bounds__(256)
void cvt_w2_kernel(const float* __restrict__ src, _Float16* __restrict__ dst)
{
    int i = blockIdx.x * 256 + threadIdx.x;      // float4 index, 1M total
    int row = (i * 4) >> 12;
    f16x4 h = { (_Float16)0.f, (_Float16)0.f, (_Float16)0.f, (_Float16)0.f };
    if (row < 1000) {
        float4 v = ((const float4*)src)[i];
        h = f16x4{ (_Float16)v.x, (_Float16)v.y, (_Float16)v.z, (_Float16)v.w };
    }
    ((f16x4*)dst)[i] = h;
}

// priors [2048,4096] fp32 -> priorsT [4096,2048] fp16 (tiled transpose).
__global__ __launch_bounds__(256)
void cvt_t_kernel(const float* __restrict__ src, _Float16* __restrict__ dst)
{
    __shared__ float t[32][33];
    const int tx = threadIdx.x, ty = threadIdx.y;
    const int c0 = blockIdx.x * 32, r0 = blockIdx.y * 32;
#pragma unroll
    for (int j = 0; j < 4; ++j)
        t[ty + 8*j][tx] = src[(size_t)(r0 + ty + 8*j) * 4096 + c0 + tx];
    __syncthreads();
#pragma unroll
    for (int j = 0; j < 4; ++j)
        dst[(size_t)(c0 + ty + 8*j) * 2048 + r0 + tx] = (_Float16)t[tx][ty + 8*j];
}

// ---------------------------------------------------------------------------
// Streaming VAE elementwise kernels (replace gemm EPI=2 / EPI=5 epilogues).
// One (half-)row per block; all accesses coalesced 16-32B/lane.
// ---------------------------------------------------------------------------

// w = 1 + sqrt(exp(lv)) * eps_w[g];  lv fp32 [2048,2048].
// Writes w16 (fp16, GEMM3 input), out_w (fp32), out_var (fp32).
__global__ __launch_bounds__(256)
void ew_w_kernel(const float* __restrict__ lv, const float* __restrict__ eps_w,
                 const int* __restrict__ perm, _Float16* __restrict__ w16,
                 float* __restrict__ out_w, float* __restrict__ out_var)
{
    const int r  = blockIdx.x;                 // 0..2047
    const int g  = perm[2048 + r];             // original row index
    const int c0 = threadIdx.x * 8;            // 256 threads * 8 = 2048 cols
    const size_t ro = (size_t)r * 2048 + c0;
    const size_t go = (size_t)g * 2048 + c0;
    float4 l0 = *(const float4*)(lv + ro);
    float4 l1 = *(const float4*)(lv + ro + 4);
    float4 e0 = *(const float4*)(eps_w + go);
    float4 e1 = *(const float4*)(eps_w + go + 4);
    float lvv[8] = { l0.x, l0.y, l0.z, l0.w, l1.x, l1.y, l1.z, l1.w };
    float ev[8]  = { e0.x, e0.y, e0.z, e0.w, e1.x, e1.y, e1.z, e1.w };
    float wv[8], vv[8];
    f16x8 wh;
#pragma unroll
    for (int j = 0; j < 8; ++j) {
        vv[j] = __expf(lvv[j]);
        wv[j] = fmaf(sqrtf(vv[j]), ev[j], 1.f);
        wh[j] = (_Float16)wv[j];
    }
    *(f16x8*)(w16 + ro) = wh;
    *(float4*)(out_w + ro)       = make_float4(wv[0], wv[1], wv[2], wv[3]);
    *(float4*)(out_w + ro + 4)   = make_float4(wv[4], wv[5], wv[6], wv[7]);
    *(float4*)(out_var + ro)     = make_float4(vv[0], vv[1], vv[2], vv[3]);
    *(float4*)(out_var + ro + 4) = make_float4(vv[4], vv[5], vv[6], vv[7]);
}

// In-place on comb16 bottom half: lr(fp16) -> x_rec * softplus(mean + exp(0.5*lr)*eps_r[g]).
__global__ __launch_bounds__(512)
void ew_reg_kernel(_Float16* __restrict__ comb_bot,
                   const _Float16* __restrict__ mean,
                   const _Float16* __restrict__ xrec,
                   const float* __restrict__ eps_r,
                   const int* __restrict__ perm)
{
    const int r  = blockIdx.x;                 // 0..2047
    const int g  = perm[2048 + r];
    const int c0 = threadIdx.x * 8;            // 512 threads * 8 = 4096 cols
    const size_t ro = (size_t)r * 4096 + c0;
    const size_t go = (size_t)g * 4096 + c0;
    f16x8 lr = *(const f16x8*)(comb_bot + ro);
    f16x8 mn = *(const f16x8*)(mean + ro);
    f16x8 xr = *(const f16x8*)(xrec + ro);
    float4 e0 = *(const float4*)(eps_r + go);
    float4 e1 = *(const float4*)(eps_r + go + 4);
    float ev[8] = { e0.x, e0.y, e0.z, e0.w, e1.x, e1.y, e1.z, e1.w };
    f16x8 ov;
#pragma unroll
    for (int j = 0; j < 8; ++j) {
        float sd = __expf(0.5f * (float)lr[j]);
        float z  = fmaf(sd, ev[j], (float)mn[j]);
        float sp = fmaxf(z, 0.f) + __logf(1.f + __expf(-fabsf(z)));
        ov[j] = (_Float16)((float)xr[j] * sp);
    }
    *(f16x8*)(comb_bot + ro) = ov;
}

// ---------------------------------------------------------------------------
// fp16 MFMA GEMM: C = A[M,K] @ B[N,K]^T (+epilogue). BM=BN=128, BK=32,
// 128 threads = 2 waves; wave tile 128x64 = 4x2 of 32x32x16 MFMA tiles.
// EPI: 0 ->C16; 1 relu+bias->C16; 3 bias->C16; 7 bias->Cf (guard gc<Nc).
// ---------------------------------------------------------------------------
template <int EPI>
__global__ __launch_bounds__(128, 2)
void gemm16(const _Float16* __restrict__ A, const _Float16* __restrict__ B,
            _Float16* __restrict__ C16, float* __restrict__ Cf,
            int M, int N, int K, int Nc,
            const float* __restrict__ bias)
{
    __shared__ _Float16 As[128 * 32];
    __shared__ _Float16 Bs[128 * 32];
    const int t    = threadIdx.x;
    const int lane = t & 63;
    const int wid  = t >> 6;            // 0..1
    const int row0 = blockIdx.y * 128;
    const int col0 = blockIdx.x * 128;

    f32x16 acc[4][2];
#pragma unroll
    for (int i = 0; i < 4; ++i)
#pragma unroll
        for (int j = 0; j < 2; ++j)
#pragma unroll
            for (int r = 0; r < 16; ++r) acc[i][j][r] = 0.f;

    // Staging addresses: each wave instruction covers 16 rows x 32 k (fp16).
    // LDS slot lane*16B == (r = base+lane>>2, chunk = lane&3); global chunk
    // is XOR-swizzled: c' = (lane&3) ^ (r&3).
    const _Float16* ap[4];
    const _Float16* bp[4];
    int loff[4];
#pragma unroll
    for (int i = 0; i < 4; ++i) {
        int r  = wid * 64 + i * 16 + (lane >> 2);
        int cc = (lane & 3) ^ (r & 3);
        ap[i]   = A + (size_t)(row0 + r) * K + cc * 8;
        bp[i]   = B + (size_t)(col0 + r) * K + cc * 8;
        loff[i] = (wid * 64 + i * 16) * 32;
    }

    for (int k0 = 0; k0 < K; k0 += 32) {
#pragma unroll
        for (int i = 0; i < 4; ++i) {
            load_lds16(ap[i], &As[loff[i]]);
            load_lds16(bp[i], &Bs[loff[i]]);
            ap[i] += 32; bp[i] += 32;
        }
        __syncthreads();
#pragma unroll
        for (int ks = 0; ks < 2; ++ks) {
            f16x8 af[4], bf[2];
#pragma unroll
            for (int ti = 0; ti < 4; ++ti) {
                int r = ti * 32 + (lane & 31);
                int c = (ks * 2 + (lane >> 5)) ^ (r & 3);
                af[ti] = *(const f16x8*)&As[r * 32 + c * 8];
            }
#pragma unroll
            for (int tj = 0; tj < 2; ++tj) {
                int n = wid * 64 + tj * 32 + (lane & 31);
                int c = (ks * 2 + (lane >> 5)) ^ (n & 3);
                bf[tj] = *(const f16x8*)&Bs[n * 32 + c * 8];
            }
#pragma unroll
            for (int ti = 0; ti < 4; ++ti)
#pragma unroll
                for (int tj = 0; tj < 2; ++tj)
                    acc[ti][tj] = __builtin_amdgcn_mfma_f32_32x32x16_f16(
                        af[ti], bf[tj], acc[ti][tj], 0, 0, 0);
        }
        __syncthreads();
    }

    // Epilogue. C/D layout (32x32): col = lane&31, row = (reg&3)+8*(reg>>2)+4*(lane>>5).
    const int ln = lane & 31;
    const int lh = lane >> 5;
#pragma unroll
    for (int ti = 0; ti < 4; ++ti) {
#pragma unroll
        for (int tj = 0; tj < 2; ++tj) {
            const int gc = col0 + wid * 64 + tj * 32 + ln;
#pragma unroll
            for (int reg = 0; reg < 16; ++reg) {
                const int gr = row0 + ti * 32 + (reg & 3) + 8 * (reg >> 2) + 4 * lh;
                const float v = acc[ti][tj][reg];
                if constexpr (EPI == 0) {
                    C16[(size_t)gr * N + gc] = (_Float16)v;
                } else if constexpr (EPI == 1) {
                    C16[(size_t)gr * N + gc] = (_Float16)fmaxf(v + bias[gc], 0.f);
                } else if constexpr (EPI == 3) {
                    C16[(size_t)gr * N + gc] = (_Float16)(v + bias[gc]);
                } else if constexpr (EPI == 7) {
                    if (gc < Nc) Cf[(size_t)gr * Nc + gc] = v + bias[gc];
                }
            }
        }
    }
}

extern "C" void kernel_launch(void* const* d_in, const int* in_sizes, int n_in,
                              void* d_out, int out_size, void* d_ws, size_t ws_size,
                              hipStream_t stream)
{
    (void)in_sizes; (void)n_in; (void)out_size; (void)ws_size;

    const float* x      = (const float*)d_in[0];
    const int*   mm     = (const int*)  d_in[1];
    const float* priors = (const float*)d_in[2];
    const float* W1  = (const float*)d_in[3];
    const float* b1  = (const float*)d_in[4];
    const float* W2  = (const float*)d_in[5];
    const float* b2  = (const float*)d_in[6];
    const float* Wr1 = (const float*)d_in[7];
    const float* br1 = (const float*)d_in[8];
    const float* Wlv = (const float*)d_in[9];
    const float* blv = (const float*)d_in[10];
    const float* Wg1 = (const float*)d_in[11];
    const float* bg1 = (const float*)d_in[12];
    const float* Wm  = (const float*)d_in[13];
    const float* bm  = (const float*)d_in[14];
    const float* Wl  = (const float*)d_in[15];
    const float* bl  = (const float*)d_in[16];
    const float* eps_w = (const float*)d_in[17];
    const float* eps_r = (const float*)d_in[18];

    float* out        = (float*)d_out;
    float* out_logits = out;                           // 4096x1000
    float* out_w      = out + (size_t)4096 * 1000;     // 2048x2048
    float* out_var    = out_w + (size_t)2048 * 2048;   // 2048x2048

    // Workspace layout (~288 MB):
    int* perm = (int*)d_ws;
    char* base = (char*)d_ws + 32768;
    _Float16* wr1h  = (_Float16*)(base);                    // 32 MB
    _Float16* wlvh  = (_Float16*)(base + 33554432);         // 16 MB
    _Float16* priTh = (_Float16*)(base + 50331648);         // 16 MB [4096,2048]
    _Float16* wg1h  = (_Float16*)(base + 67108864);         // 32 MB
    _Float16* wmh   = (_Float16*)(base + 100663296);        // 32 MB
    _Float16* wlh   = (_Float16*)(base + 134217728);        // 32 MB
    _Float16* w1h   = (_Float16*)(base + 167772160);        // 32 MB
    _Float16* w2ph  = (_Float16*)(base + 201326592);        // 8 MB [1024,4096]
    char* acts = base + 209715200;
    _Float16* xm16   = (_Float16*)(acts);                   // 16 MB (xrec16 alias)
    _Float16* h16    = (_Float16*)(acts + 16777216);        // 16 MB (hr16 alias)
    _Float16* w16    = (_Float16*)(acts + 33554432);        //  8 MB
    _Float16* mtmp16 = (_Float16*)(acts + 41943040);        // 16 MB (lvf alias)
    _Float16* comb16 = (_Float16*)(acts + 58720256);        // 32 MB
    _Float16* xrec16 = xm16;    // x_m dead after gemm1
    _Float16* hr16   = h16;     // h dead after gemm2
    _Float16* h1_16  = xm16;    // branch dead after ew_reg (32 MB over xm16+h16)
    float*    lvf    = (float*)mtmp16;                      // fp32 [2048,2048] = 16 MB,
                                                            // dead before gemm 5a writes mtmp16
    _Float16* comb_bot = comb16 + (size_t)2048 * 4096;

    perm_kernel<<<1, 1024, 0, stream>>>(mm, perm);

    // Weight conversions (fp32 -> fp16), ~600 MB HBM traffic total.
    cvt_kernel<<<16384, 256, 0, stream>>>(Wr1, wr1h, 4194304);
    cvt_kernel<<< 8192, 256, 0, stream>>>(Wlv, wlvh, 2097152);
    cvt_t_kernel<<<dim3(128, 64), dim3(32, 8), 0, stream>>>(priors, priTh);
    cvt_kernel<<<16384, 256, 0, stream>>>(Wg1, wg1h, 4194304);
    cvt_kernel<<<16384, 256, 0, stream>>>(Wm,  wmh,  4194304);
    cvt_kernel<<<16384, 256, 0, stream>>>(Wl,  wlh,  4194304);
    cvt_kernel<<<16384, 256, 0, stream>>>(W1,  w1h,  4194304);
    cvt_w2_kernel<<<4096, 256, 0, stream>>>(W2, w2ph);

    gather_kernel<<<dim3(4, 4096), 256, 0, stream>>>(x, perm, comb16, xm16);

    // 1: h = relu(x_m @ Wr1^T + br1)          [2048,4096] K=4096
    gemm16<1><<<dim3(32, 16), 128, 0, stream>>>(
        xm16, wr1h, h16, nullptr, 2048, 4096, 4096, 4096, br1);
    // 2: logvar = h @ Wlv^T + blv -> fp32     [2048,2048] K=4096
    gemm16<7><<<dim3(16, 16), 128, 0, stream>>>(
        h16, wlvh, nullptr, lvf, 2048, 2048, 4096, 2048, blv);
    // 2b: w/var elementwise (streaming)
    ew_w_kernel<<<2048, 256, 0, stream>>>(lvf, eps_w, perm, w16, out_w, out_var);
    // 3: x_rec = w @ priors                    [2048,4096] K=2048
    gemm16<0><<<dim3(32, 16), 128, 0, stream>>>(
        w16, priTh, xrec16, nullptr, 2048, 4096, 2048, 4096, nullptr);
    // 4: hr = relu(x_rec @ Wg1^T + bg1)
    gemm16<1><<<dim3(32, 16), 128, 0, stream>>>(
        xrec16, wg1h, hr16, nullptr, 2048, 4096, 4096, 4096, bg1);
    // 5a: mean_reg -> mtmp16 (fp16)
    gemm16<3><<<dim3(32, 16), 128, 0, stream>>>(
        hr16, wmh, mtmp16, nullptr, 2048, 4096, 4096, 4096, bm);
    // 5b: lr = hr @ Wl^T + bl -> comb16 bottom (fp16, in place)
    gemm16<3><<<dim3(32, 16), 128, 0, stream>>>(
        hr16, wlh, comb_bot, nullptr, 2048, 4096, 4096, 4096, bl);
    // 5c: x_reg = x_rec * softplus(mean + exp(0.5*lr)*eps_r) (in place, streaming)
    ew_reg_kernel<<<2048, 512, 0, stream>>>(comb_bot, mtmp16, xrec16, eps_r, perm);
    // 6: h1 = relu(comb @ W1^T + b1)           [4096,4096] K=4096
    gemm16<1><<<dim3(32, 32), 128, 0, stream>>>(
        comb16, w1h, h1_16, nullptr, 4096, 4096, 4096, 4096, b1);
    // 7: logits = h1 @ W2^T + b2 (fp32 out, guard gc<1000)
    gemm16<7><<<dim3(8, 32), 128, 0, stream>>>(
        h1_16, w2ph, nullptr, out_logits, 4096, 1024, 4096, 1000, b2);
}

// Round 2
// 1281.298 us; speedup vs baseline: 1.8287x; 1.2256x over previous
//
#include <hip/hip_runtime.h>
#include <cmath>
#include <cstddef>
#include <cstdint>

// ---------------------------------------------------------------------------
// Round 4: upgrade the GEMM core. rocprof (R3) showed gemm6 (4096^3) at
// ~197us = 700 TF with MfmaUtil 30%, Occupancy 20%, SQ_LDS_BANK_CONFLICT
// 3.8e7 (8-way: BK=32 rows are 64B/16 banks, 4-slot XOR leaves 4 bank-quads
// for 32 lanes). New core: 256 thr / 4 waves (2x2 of 64x64/wave), BK=64,
// full-row 8-chunk XOR swizzle (row=128B=all 32 banks -> 4-way residual,
// m136: 1.58x vs 2.94x), half the barrier drains per K. Same single-buffer
// 2-barrier structure (proven-correct semantics, m97-class ~900 TF target).
// Also: 6 flat weight cvts merged into one launch.
// ---------------------------------------------------------------------------

typedef _Float16 f16x8 __attribute__((ext_vector_type(8)));
typedef _Float16 f16x4 __attribute__((ext_vector_type(4)));
typedef float    f32x16 __attribute__((ext_vector_type(16)));

__device__ __forceinline__ void load_lds16(const _Float16* g, _Float16* l)
{
    __builtin_amdgcn_global_load_lds(
        (const __attribute__((address_space(1))) void*)g,
        (__attribute__((address_space(3))) void*)l, 16, 0, 0);
}

// Stable binary argsort of mask (mm%2): perm = [evens..., odds...].
__global__ __launch_bounds__(1024)
void perm_kernel(const int* __restrict__ mm, int* __restrict__ perm)
{
    __shared__ int sdata[1024];
    const int t = threadIdx.x;
    int m[4]; int cnt = 0;
#pragma unroll
    for (int j = 0; j < 4; ++j) { int i = t*4 + j; m[j] = mm[i] & 1; cnt += m[j]; }
    sdata[t] = cnt;
    __syncthreads();
    for (int off = 1; off < 1024; off <<= 1) {
        int v = (t >= off) ? sdata[t - off] : 0;
        __syncthreads();
        sdata[t] += v;
        __syncthreads();
    }
    const int n0 = 4096 - sdata[1023];
    int ones_before  = sdata[t] - cnt;
    int zeros_before = t*4 - ones_before;
#pragma unroll
    for (int j = 0; j < 4; ++j) {
        int i = t*4 + j;
        if (m[j]) perm[n0 + (ones_before++)] = i;
        else      perm[(zeros_before++)]     = i;
    }
}

// x fp32 -> comb16 top half (unmasked rows) and xm16 (masked rows), fp16.
__global__ __launch_bounds__(256)
void gather_kernel(const float* __restrict__ x, const int* __restrict__ perm,
                   _Float16* __restrict__ comb, _Float16* __restrict__ xm)
{
    const int p  = blockIdx.y;
    const int c4 = blockIdx.x * 256 + threadIdx.x;   // float4 col 0..1023
    const int src = perm[p];
    const float4 v = *(const float4*)(x + (size_t)src * 4096 + (size_t)c4 * 4);
    f16x4 h = { (_Float16)v.x, (_Float16)v.y, (_Float16)v.z, (_Float16)v.w };
    if (p < 2048) *(f16x4*)(comb + (size_t)p * 4096 + (size_t)c4 * 4) = h;
    else          *(f16x4*)(xm + (size_t)(p - 2048) * 4096 + (size_t)c4 * 4) = h;
}

// All six flat weight matrices fp32 -> fp16 in one launch (22M float4).
__global__ __launch_bounds__(256)
void cvt_all_kernel(const float* __restrict__ Wr1, const float* __restrict__ Wlv,
                    const float* __restrict__ Wg1, const float* __restrict__ Wm,
                    const float* __restrict__ Wl,  const float* __restrict__ W1,
                    _Float16* __restrict__ wr1h, _Float16* __restrict__ wlvh,
                    _Float16* __restrict__ wg1h, _Float16* __restrict__ wmh,
                    _Float16* __restrict__ wlh,  _Float16* __restrict__ w1h)
{
    int i = blockIdx.x * 256 + threadIdx.x;          // float4 index
    const float* s; _Float16* d; int off;
    if      (i <  4194304) { s = Wr1; d = wr1h; off = 0; }
    else if (i <  6291456) { s = Wlv; d = wlvh; off =  4194304; }
    else if (i < 10485760) { s = Wg1; d = wg1h; off =  6291456; }
    else if (i < 14680064) { s = Wm;  d = wmh;  off = 10485760; }
    else if (i < 18874368) { s = Wl;  d = wlh;  off = 14680064; }
    else                   { s = W1;  d = w1h;  off = 18874368; }
    int j = i - off;
    float4 v = ((const float4*)s)[j];
    f16x4 h = { (_Float16)v.x, (_Float16)v.y, (_Float16)v.z, (_Float16)v.w };
    ((f16x4*)d)[j] = h;
}

// W2 [1000,4096] fp32 -> [1024,4096] fp16, rows 1000..1023 zeroed.
__global__ __launch_bounds__(256)
void cvt_w2_kernel(const float* __restrict__ src, _Float16* __restrict__ dst)
{
    int i = blockIdx.x * 256 + threadIdx.x;      // float4 index, 1M total
    int row = (i * 4) >> 12;
    f16x4 h = { (_Float16)0.f, (_Float16)0.f, (_Float16)0.f, (_Float16)0.f };
    if (row < 1000) {
        float4 v = ((const float4*)src)[i];
        h = f16x4{ (_Float16)v.x, (_Float16)v.y, (_Float16)v.z, (_Float16)v.w };
    }
    ((f16x4*)dst)[i] = h;
}

// priors [2048,4096] fp32 -> priorsT [4096,2048] fp16 (tiled transpose).
__global__ __launch_bounds__(256)
void cvt_t_kernel(const float* __restrict__ src, _Float16* __restrict__ dst)
{
    __shared__ float t[32][33];
    const int tx = threadIdx.x, ty = threadIdx.y;
    const int c0 = blockIdx.x * 32, r0 = blockIdx.y * 32;
#pragma unroll
    for (int j = 0; j < 4; ++j)
        t[ty + 8*j][tx] = src[(size_t)(r0 + ty + 8*j) * 4096 + c0 + tx];
    __syncthreads();
#pragma unroll
    for (int j = 0; j < 4; ++j)
        dst[(size_t)(c0 + ty + 8*j) * 2048 + r0 + tx] = (_Float16)t[tx][ty + 8*j];
}

// ---------------------------------------------------------------------------
// Streaming VAE elementwise kernels.
// ---------------------------------------------------------------------------

// w = 1 + sqrt(exp(lv)) * eps_w[g];  lv fp32 [2048,2048].
__global__ __launch_bounds__(256)
void ew_w_kernel(const float* __restrict__ lv, const float* __restrict__ eps_w,
                 const int* __restrict__ perm, _Float16* __restrict__ w16,
                 float* __restrict__ out_w, float* __restrict__ out_var)
{
    const int r  = blockIdx.x;                 // 0..2047
    const int g  = perm[2048 + r];             // original row index
    const int c0 = threadIdx.x * 8;            // 256 threads * 8 = 2048 cols
    const size_t ro = (size_t)r * 2048 + c0;
    const size_t go = (size_t)g * 2048 + c0;
    float4 l0 = *(const float4*)(lv + ro);
    float4 l1 = *(const float4*)(lv + ro + 4);
    float4 e0 = *(const float4*)(eps_w + go);
    float4 e1 = *(const float4*)(eps_w + go + 4);
    float lvv[8] = { l0.x, l0.y, l0.z, l0.w, l1.x, l1.y, l1.z, l1.w };
    float ev[8]  = { e0.x, e0.y, e0.z, e0.w, e1.x, e1.y, e1.z, e1.w };
    float wv[8], vv[8];
    f16x8 wh;
#pragma unroll
    for (int j = 0; j < 8; ++j) {
        vv[j] = __expf(lvv[j]);
        wv[j] = fmaf(sqrtf(vv[j]), ev[j], 1.f);
        wh[j] = (_Float16)wv[j];
    }
    *(f16x8*)(w16 + ro) = wh;
    *(float4*)(out_w + ro)       = make_float4(wv[0], wv[1], wv[2], wv[3]);
    *(float4*)(out_w + ro + 4)   = make_float4(wv[4], wv[5], wv[6], wv[7]);
    *(float4*)(out_var + ro)     = make_float4(vv[0], vv[1], vv[2], vv[3]);
    *(float4*)(out_var + ro + 4) = make_float4(vv[4], vv[5], vv[6], vv[7]);
}

// In-place on comb16 bottom half: lr(fp16) -> x_rec * softplus(mean + exp(0.5*lr)*eps_r[g]).
__global__ __launch_bounds__(512)
void ew_reg_kernel(_Float16* __restrict__ comb_bot,
                   const _Float16* __restrict__ mean,
                   const _Float16* __restrict__ xrec,
                   const float* __restrict__ eps_r,
                   const int* __restrict__ perm)
{
    const int r  = blockIdx.x;                 // 0..2047
    const int g  = perm[2048 + r];
    const int c0 = threadIdx.x * 8;            // 512 threads * 8 = 4096 cols
    const size_t ro = (size_t)r * 4096 + c0;
    const size_t go = (size_t)g * 4096 + c0;
    f16x8 lr = *(const f16x8*)(comb_bot + ro);
    f16x8 mn = *(const f16x8*)(mean + ro);
    f16x8 xr = *(const f16x8*)(xrec + ro);
    float4 e0 = *(const float4*)(eps_r + go);
    float4 e1 = *(const float4*)(eps_r + go + 4);
    float ev[8] = { e0.x, e0.y, e0.z, e0.w, e1.x, e1.y, e1.z, e1.w };
    f16x8 ov;
#pragma unroll
    for (int j = 0; j < 8; ++j) {
        float sd = __expf(0.5f * (float)lr[j]);
        float z  = fmaf(sd, ev[j], (float)mn[j]);
        float sp = fmaxf(z, 0.f) + __logf(1.f + __expf(-fabsf(z)));
        ov[j] = (_Float16)((float)xr[j] * sp);
    }
    *(f16x8*)(comb_bot + ro) = ov;
}

// ---------------------------------------------------------------------------
// fp16 MFMA GEMM: C = A[M,K] @ B[N,K]^T (+epilogue). BM=BN=128, BK=64,
// 256 threads = 4 waves in 2x2; wave tile 64x64 = 2x2 of 32x32x16 MFMA.
// LDS rows are 128B (all 32 banks); 16B chunk c stored at slot c ^ (r&7)
// -> ds_read_b128 fragment reads are 4-way max (m136: 1.58x, vs 8-way 2.94x).
// global_load_lds dest is linear (wave-uniform base + lane*16); the XOR is
// applied to the per-lane GLOBAL source address (guide m173 pattern).
// EPI: 0 ->C16; 1 relu+bias->C16; 3 bias->C16; 7 bias->Cf (guard gc<Nc).
// ---------------------------------------------------------------------------
template <int EPI>
__global__ __launch_bounds__(256, 3)
void gemm16(const _Float16* __restrict__ A, const _Float16* __restrict__ B,
            _Float16* __restrict__ C16, float* __restrict__ Cf,
            int M, int N, int K, int Nc,
            const float* __restrict__ bias)
{
    __shared__ _Float16 As[128 * 64];
    __shared__ _Float16 Bs[128 * 64];
    const int t    = threadIdx.x;
    const int lane = t & 63;
    const int wid  = t >> 6;            // 0..3
    const int wr   = wid >> 1;          // wave row 0..1
    const int wc   = wid & 1;           // wave col 0..1
    const int row0 = blockIdx.y * 128;
    const int col0 = blockIdx.x * 128;

    f32x16 acc[2][2];
#pragma unroll
    for (int i = 0; i < 2; ++i)
#pragma unroll
        for (int j = 0; j < 2; ++j)
#pragma unroll
            for (int r = 0; r < 16; ++r) acc[i][j][r] = 0.f;

    // Staging: 1024 16B chunks per matrix per K-step; thread t, iter i covers
    // chunk n = i*256 + t -> LDS row r = n>>3, slot cc = n&7. The logical
    // k-chunk is c = cc ^ (r&7); global src = row r, k-offset c*8.
    const _Float16* ap[4];
    const _Float16* bp[4];
    int loff[4];
#pragma unroll
    for (int i = 0; i < 4; ++i) {
        int n  = i * 256 + t;
        int r  = n >> 3;
        int c  = (n & 7) ^ (r & 7);
        ap[i]   = A + (size_t)(row0 + r) * K + c * 8;
        bp[i]   = B + (size_t)(col0 + r) * K + c * 8;
        loff[i] = (i * 256 + wid * 64) * 8;   // wave-uniform LDS base (fp16 elems)
    }

    const int ln = lane & 31;
    const int lh = lane >> 5;

    for (int k0 = 0; k0 < K; k0 += 64) {
#pragma unroll
        for (int i = 0; i < 4; ++i) {
            load_lds16(ap[i], &As[loff[i]]);
            load_lds16(bp[i], &Bs[loff[i]]);
            ap[i] += 64; bp[i] += 64;
        }
        __syncthreads();
#pragma unroll
        for (int ks = 0; ks < 4; ++ks) {
            f16x8 af[2], bf[2];
#pragma unroll
            for (int ti = 0; ti < 2; ++ti) {
                int r = wr * 64 + ti * 32 + ln;
                int c = (ks * 2 + lh) ^ (r & 7);
                af[ti] = *(const f16x8*)&As[r * 64 + c * 8];
            }
#pragma unroll
            for (int tj = 0; tj < 2; ++tj) {
                int n = wc * 64 + tj * 32 + ln;
                int c = (ks * 2 + lh) ^ (n & 7);
                bf[tj] = *(const f16x8*)&Bs[n * 64 + c * 8];
            }
#pragma unroll
            for (int ti = 0; ti < 2; ++ti)
#pragma unroll
                for (int tj = 0; tj < 2; ++tj)
                    acc[ti][tj] = __builtin_amdgcn_mfma_f32_32x32x16_f16(
                        af[ti], bf[tj], acc[ti][tj], 0, 0, 0);
        }
        __syncthreads();
    }

    // Epilogue. C/D layout (32x32): col = lane&31, row = (reg&3)+8*(reg>>2)+4*(lane>>5).
#pragma unroll
    for (int ti = 0; ti < 2; ++ti) {
#pragma unroll
        for (int tj = 0; tj < 2; ++tj) {
            const int gc = col0 + wc * 64 + tj * 32 + ln;
#pragma unroll
            for (int reg = 0; reg < 16; ++reg) {
                const int gr = row0 + wr * 64 + ti * 32
                             + (reg & 3) + 8 * (reg >> 2) + 4 * lh;
                const float v = acc[ti][tj][reg];
                if constexpr (EPI == 0) {
                    C16[(size_t)gr * N + gc] = (_Float16)v;
                } else if constexpr (EPI == 1) {
                    C16[(size_t)gr * N + gc] = (_Float16)fmaxf(v + bias[gc], 0.f);
                } else if constexpr (EPI == 3) {
                    C16[(size_t)gr * N + gc] = (_Float16)(v + bias[gc]);
                } else if constexpr (EPI == 7) {
                    if (gc < Nc) Cf[(size_t)gr * Nc + gc] = v + bias[gc];
                }
            }
        }
    }
}

extern "C" void kernel_launch(void* const* d_in, const int* in_sizes, int n_in,
                              void* d_out, int out_size, void* d_ws, size_t ws_size,
                              hipStream_t stream)
{
    (void)in_sizes; (void)n_in; (void)out_size; (void)ws_size;

    const float* x      = (const float*)d_in[0];
    const int*   mm     = (const int*)  d_in[1];
    const float* priors = (const float*)d_in[2];
    const float* W1  = (const float*)d_in[3];
    const float* b1  = (const float*)d_in[4];
    const float* W2  = (const float*)d_in[5];
    const float* b2  = (const float*)d_in[6];
    const float* Wr1 = (const float*)d_in[7];
    const float* br1 = (const float*)d_in[8];
    const float* Wlv = (const float*)d_in[9];
    const float* blv = (const float*)d_in[10];
    const float* Wg1 = (const float*)d_in[11];
    const float* bg1 = (const float*)d_in[12];
    const float* Wm  = (const float*)d_in[13];
    const float* bm  = (const float*)d_in[14];
    const float* Wl  = (const float*)d_in[15];
    const float* bl  = (const float*)d_in[16];
    const float* eps_w = (const float*)d_in[17];
    const float* eps_r = (const float*)d_in[18];

    float* out        = (float*)d_out;
    float* out_logits = out;                           // 4096x1000
    float* out_w      = out + (size_t)4096 * 1000;     // 2048x2048
    float* out_var    = out_w + (size_t)2048 * 2048;   // 2048x2048

    // Workspace layout (~288 MB):
    int* perm = (int*)d_ws;
    char* base = (char*)d_ws + 32768;
    _Float16* wr1h  = (_Float16*)(base);                    // 32 MB
    _Float16* wlvh  = (_Float16*)(base + 33554432);         // 16 MB
    _Float16* priTh = (_Float16*)(base + 50331648);         // 16 MB [4096,2048]
    _Float16* wg1h  = (_Float16*)(base + 67108864);         // 32 MB
    _Float16* wmh   = (_Float16*)(base + 100663296);        // 32 MB
    _Float16* wlh   = (_Float16*)(base + 134217728);        // 32 MB
    _Float16* w1h   = (_Float16*)(base + 167772160);        // 32 MB
    _Float16* w2ph  = (_Float16*)(base + 201326592);        // 8 MB [1024,4096]
    char* acts = base + 209715200;
    _Float16* xm16   = (_Float16*)(acts);                   // 16 MB (xrec16 alias)
    _Float16* h16    = (_Float16*)(acts + 16777216);        // 16 MB (hr16 alias)
    _Float16* w16    = (_Float16*)(acts + 33554432);        //  8 MB
    _Float16* mtmp16 = (_Float16*)(acts + 41943040);        // 16 MB (lvf alias)
    _Float16* comb16 = (_Float16*)(acts + 58720256);        // 32 MB
    _Float16* xrec16 = xm16;    // x_m dead after gemm1
    _Float16* hr16   = h16;     // h dead after gemm2
    _Float16* h1_16  = xm16;    // branch dead after ew_reg (32 MB over xm16+h16)
    float*    lvf    = (float*)mtmp16;                      // fp32 [2048,2048] = 16 MB,
                                                            // dead before gemm 5a writes mtmp16
    _Float16* comb_bot = comb16 + (size_t)2048 * 4096;

    perm_kernel<<<1, 1024, 0, stream>>>(mm, perm);

    // Weight conversions (fp32 -> fp16), ~600 MB HBM traffic total.
    cvt_all_kernel<<<90112, 256, 0, stream>>>(Wr1, Wlv, Wg1, Wm, Wl, W1,
                                              wr1h, wlvh, wg1h, wmh, wlh, w1h);
    cvt_t_kernel<<<dim3(128, 64), dim3(32, 8), 0, stream>>>(priors, priTh);
    cvt_w2_kernel<<<4096, 256, 0, stream>>>(W2, w2ph);

    gather_kernel<<<dim3(4, 4096), 256, 0, stream>>>(x, perm, comb16, xm16);

    // 1: h = relu(x_m @ Wr1^T + br1)          [2048,4096] K=4096
    gemm16<1><<<dim3(32, 16), 256, 0, stream>>>(
        xm16, wr1h, h16, nullptr, 2048, 4096, 4096, 4096, br1);
    // 2: logvar = h @ Wlv^T + blv -> fp32     [2048,2048] K=4096
    gemm16<7><<<dim3(16, 16), 256, 0, stream>>>(
        h16, wlvh, nullptr, lvf, 2048, 2048, 4096, 2048, blv);
    // 2b: w/var elementwise (streaming)
    ew_w_kernel<<<2048, 256, 0, stream>>>(lvf, eps_w, perm, w16, out_w, out_var);
    // 3: x_rec = w @ priors                    [2048,4096] K=2048
    gemm16<0><<<dim3(32, 16), 256, 0, stream>>>(
        w16, priTh, xrec16, nullptr, 2048, 4096, 2048, 4096, nullptr);
    // 4: hr = relu(x_rec @ Wg1^T + bg1)
    gemm16<1><<<dim3(32, 16), 256, 0, stream>>>(
        xrec16, wg1h, hr16, nullptr, 2048, 4096, 4096, 4096, bg1);
    // 5a: mean_reg -> mtmp16 (fp16)
    gemm16<3><<<dim3(32, 16), 256, 0, stream>>>(
        hr16, wmh, mtmp16, nullptr, 2048, 4096, 4096, 4096, bm);
    // 5b: lr = hr @ Wl^T + bl -> comb16 bottom (fp16, in place)
    gemm16<3><<<dim3(32, 16), 256, 0, stream>>>(
        hr16, wlh, comb_bot, nullptr, 2048, 4096, 4096, 4096, bl);
    // 5c: x_reg = x_rec * softplus(mean + exp(0.5*lr)*eps_r) (in place, streaming)
    ew_reg_kernel<<<2048, 512, 0, stream>>>(comb_bot, mtmp16, xrec16, eps_r, perm);
    // 6: h1 = relu(comb @ W1^T + b1)           [4096,4096] K=4096
    gemm16<1><<<dim3(32, 32), 256, 0, stream>>>(
        comb16, w1h, h1_16, nullptr, 4096, 4096, 4096, 4096, b1);
    // 7: logits = h1 @ W2^T + b2 (fp32 out, guard gc<1000)
    gemm16<7><<<dim3(8, 32), 256, 0, stream>>>(
        h1_16, w2ph, nullptr, out_logits, 4096, 1024, 4096, 1000, b2);
}